// Round 8
// baseline (87.048 us; speedup 1.0000x reference)
//
#include <hip/hip_runtime.h>

#define L_LEN 4096
#define NT 1024
#define ROWS 512               // B*J = 32*16 fixed by the reference
#define SLOP 96u               // f32-key error band (fast-log/div error <= ~8 ulps; 12x margin)
#define BCAP 256
#define NW (NT / 64)           // 16 waves

typedef float     f32x4 __attribute__((ext_vector_type(4)));   // native vectors for nt ld/st
typedef int       i32x4 __attribute__((ext_vector_type(4)));
typedef long long i64x2 __attribute__((ext_vector_type(2)));

// Round 18: single-axis delta vs round 17 (best, 84.61 us = nt stores win,
// -1.95): non-temporal LOADS on the read-once input streams (w, u, ids).
// Each row is consumed by exactly one block — L2 allocation buys nothing.
// With stores already nt, this takes L2 out of the steady-state path.
// Ledger: barrier-diet -1.1 | nt-stores -2.0 | occupancy +0 | fastmath -0.4
//         | split +6.8 WORSE | 2-row pipe +3.5 WORSE. Dispatch tax ~5-7 us.
// NOT reapplied (round-9/10 cliff): hist+logf fusion, cnt-from-hist.
__global__ __launch_bounds__(NT, 8) void AttentionEssentialReinforce_51238959841470_kernel(
    const int* __restrict__ ids,       // int32 OR little-endian int64 (auto-detected)
    const float* __restrict__ amask,   // (ROWS, 2*L), only first half used
    const float* __restrict__ uin,     // (ROWS, L)
    float* __restrict__ out,           // float32: [ids | mask | -mask], n_per each
    int n_per)
{
    __shared__ unsigned int hist[4096];          // 16 KB (pass 0: 12-bit bins)
    __shared__ unsigned int h2[256];             // pass 1 bins (pre-zeroed early)
    __shared__ unsigned int s_cntw[NW], s_orw[NW], s_nhiw[NW], s_wtot[NW];
    __shared__ unsigned long long bkey[BCAP];    // band: exact f64 keys
    __shared__ int bidx[BCAP];                   // band: element indices
    __shared__ unsigned int s_remk, s_prefix, s_bn;

    const int row = blockIdx.x;
    const int tid = threadIdx.x;
    const int lane = tid & 63, wid = tid >> 6;
    const float* wrow = amask + (size_t)row * (2 * L_LEN);
    const float* urow = uin + (size_t)row * L_LEN;

    // ---- Issue the hot loads first (nt: read-once, skip L2 allocation).
    f32x4 a0 = __builtin_nontemporal_load(reinterpret_cast<const f32x4*>(wrow) + tid);
    f32x4 b0 = __builtin_nontemporal_load(reinterpret_cast<const f32x4*>(urow) + tid);
    // int64-vs-int32 id detection: LE int64 ids (<2^31) have all-zero odd words.
    unsigned odd = ((const unsigned*)ids)[2 * tid + 1];

    // Zero histograms while the loads are in flight (off the critical path).
    #pragma unroll
    for (int b = 0; b < 4096 / NT; ++b) hist[tid + b * NT] = 0u;
    if (tid < 256) h2[tid] = 0u;
    if (tid == 0) s_bn = 0u;

    // ---- Phase 1: f32 keys in registers. r = max(w,1e-30)/(-ln u) is monotone-
    // equivalent to log(max(w,1e-30))+gumbel(u); positive-float IEEE bits are
    // order-isomorphic to value. Fast math here is safe: error <= ~8 ulps,
    // covered by the SLOP band; exactness restored in the f64 refine.
    float wv[4], uv[4];
    wv[0]=a0[0]; wv[1]=a0[1]; wv[2]=a0[2]; wv[3]=a0[3];
    uv[0]=b0[0]; uv[1]=b0[1]; uv[2]=b0[2]; uv[3]=b0[3];

    unsigned key[4];
    unsigned localnz = 0;
    #pragma unroll
    for (int e = 0; e < 4; ++e) {
        key[e] = 0u;                                  // w<=0 -> bottom, never selected
        if (wv[e] > 0.0f) {
            float t = -__logf(uv[e]);
            float r = __fdividef(fmaxf(wv[e], 1e-30f), t);
            key[e] = __float_as_uint(r);
            localnz++;
        }
    }
    {
        unsigned long long bal = __ballot(odd != 0u);
        unsigned v = localnz;
        #pragma unroll
        for (int off = 32; off > 0; off >>= 1) v += __shfl_down(v, off, 64);
        if (lane == 0) { s_cntw[wid] = v; s_orw[wid] = (bal != 0ull) ? 1u : 0u; }
    }
    __syncthreads();                                  // covers keys' wave sums + zeroing

    unsigned cnt = 0, orr = 0;
    #pragma unroll
    for (int w2 = 0; w2 < NW; ++w2) { cnt += s_cntw[w2]; orr |= s_orw[w2]; }
    const bool is64 = (orr == 0u);
    const int k = (int)floorf(0.15f * (float)cnt);    // f32(0.15)*f32(cnt), floored (as np)

    // Prefetch ids now (nt): L2 latency overlaps the radix passes below.
    int ida[4];
    if (!is64) {
        i32x4 t0 = __builtin_nontemporal_load(
            reinterpret_cast<const i32x4*>(ids + (size_t)row * L_LEN) + tid);
        ida[0]=t0[0]; ida[1]=t0[1]; ida[2]=t0[2]; ida[3]=t0[3];
    } else {
        const i64x2* idr = reinterpret_cast<const i64x2*>(
            (const long long*)ids + (size_t)row * L_LEN);
        i64x2 a = __builtin_nontemporal_load(idr + 2 * tid);
        i64x2 b = __builtin_nontemporal_load(idr + 2 * tid + 1);
        ida[0]=(int)a[0]; ida[1]=(int)a[1]; ida[2]=(int)b[0]; ida[3]=(int)b[1];
    }

    unsigned lo_thr = 0xFFFFFFFFu, hi_thr = 0xFFFFFFFFu;   // k==0: select none
    int need = 0;
    unsigned bn = 0;

    if (k > 0) {
        // ---- Phase 2: localize the k-th largest f32 key to its 20-bit-prefix bin.
        // Pass 0: 12-bit field (bits 31:20), 4096 bins (pre-zeroed above).
        #pragma unroll
        for (int e = 0; e < 4; ++e) atomicAdd(&hist[key[e] >> 20], 1u);
        __syncthreads();
        {
            int b0i = 4095 - 4 * tid;                // 4 descending bins per thread
            unsigned c[4], lsum = 0;
            #pragma unroll
            for (int m = 0; m < 4; ++m) { c[m] = hist[b0i - m]; lsum += c[m]; }
            unsigned scan = lsum;
            #pragma unroll
            for (int off = 1; off < 64; off <<= 1) {
                unsigned o = __shfl_up(scan, (unsigned)off, 64);
                if (lane >= off) scan += o;
            }
            if (lane == 63) s_wtot[wid] = scan;
            __syncthreads();
            unsigned woff = 0;                       // inline cross-wave prefix (no barrier)
            #pragma unroll
            for (int w2 = 0; w2 < NW; ++w2) woff += (w2 < wid) ? s_wtot[w2] : 0u;
            unsigned run = woff + (scan - lsum);     // count in strictly-higher bins
            unsigned remk = (unsigned)k;
            #pragma unroll
            for (int m = 0; m < 4; ++m) {
                if (run < remk && run + c[m] >= remk) {   // exactly one (thread,m) hits
                    s_prefix = (unsigned)(b0i - m);
                    s_remk = remk - run;
                }
                run += c[m];
            }
        }
        __syncthreads();
        unsigned prefix12 = s_prefix;
        unsigned remk = s_remk;

        // Pass 1: 8-bit field (bits 19:12), 256 bins (h2, pre-zeroed), matching keys only.
        #pragma unroll
        for (int e = 0; e < 4; ++e)
            if ((key[e] >> 20) == prefix12)
                atomicAdd(&h2[(key[e] >> 12) & 0xFFu], 1u);
        __syncthreads();
        if (tid < 64) {                              // wave 0: descending-bin scan
            unsigned c[4], lsum = 0;
            #pragma unroll
            for (int m = 0; m < 4; ++m) { c[m] = h2[255 - 4 * tid - m]; lsum += c[m]; }
            unsigned scan = lsum;
            #pragma unroll
            for (int off = 1; off < 64; off <<= 1) {
                unsigned o = __shfl_up(scan, (unsigned)off, 64);
                if (tid >= off) scan += o;
            }
            unsigned run = scan - lsum;
            #pragma unroll
            for (int m = 0; m < 4; ++m) {
                if (run < remk && run + c[m] >= remk) {
                    s_prefix = (prefix12 << 8) | (unsigned)(255 - 4 * tid - m);
                }
                run += c[m];
            }
        }
        __syncthreads();
        const unsigned T20 = s_prefix;               // k-th key's 20-bit prefix
        const unsigned B_lo = T20 << 12, B_hi = (T20 << 12) | 0xFFFu;

        // ---- Error band: [B_lo - SLOP, B_hi + SLOP]. key > hi => certainly top-k;
        // key < lo => certainly not; band resolved exactly in f64 below.
        lo_thr = (B_lo > SLOP) ? B_lo - SLOP : 1u;   // >=1 excludes w<=0 sentinels
        hi_thr = B_hi + SLOP;                        // no overflow (keys <= 0x7F800000)
        unsigned nhi = 0;
        #pragma unroll
        for (int e = 0; e < 4; ++e) {
            if (key[e] > hi_thr) {
                nhi++;
            } else if (key[e] >= lo_thr) {
                unsigned pos = atomicAdd(&s_bn, 1u);
                if (pos < BCAP) {
                    double t = -log((double)uv[e]);
                    double r = (double)fmaxf(wv[e], 1e-30f) / t;   // exact-order key
                    bkey[pos] = (unsigned long long)__double_as_longlong(r);
                    bidx[pos] = 4 * tid + e;
                }
            }
        }
        {
            unsigned nv = nhi;
            #pragma unroll
            for (int off = 32; off > 0; off >>= 1) nv += __shfl_down(nv, off, 64);
            if (lane == 0) s_nhiw[wid] = nv;
        }
        __syncthreads();
        unsigned nhi_tot = 0;
        #pragma unroll
        for (int w2 = 0; w2 < NW; ++w2) nhi_tot += s_nhiw[w2];
        need = k - (int)nhi_tot;                     // >= 1; bn >= need by construction
        bn = s_bn; if (bn > BCAP) bn = BCAP;
    }

    // ---- Phase 3: selection + float32 outputs (non-temporal stores) ----
    const size_t obase = (size_t)row * L_LEN;
    float* o0 = out + obase;                      // masked ids
    float* o1 = out + (size_t)n_per + obase;      // mask
    float* o2 = out + 2 * (size_t)n_per + obase;  // -mask

    float f0[4], f1[4], f2[4];
    #pragma unroll
    for (int e = 0; e < 4; ++e) {
        bool sel;
        if (key[e] > hi_thr) {
            sel = true;
        } else if (key[e] < lo_thr) {
            sel = false;
        } else {
            // band member: rank by (f64 key desc, index asc) — stable, exact
            double t = -log((double)uv[e]);
            double r = (double)fmaxf(wv[e], 1e-30f) / t;
            unsigned long long myk = (unsigned long long)__double_as_longlong(r);
            int myi = 4 * tid + e;
            int rnk = 0;
            for (unsigned j = 0; j < bn; ++j)
                rnk += (bkey[j] > myk) || (bkey[j] == myk && bidx[j] < myi);
            sel = (rnk < need);
        }
        f0[e] = sel ? 103.0f : (float)ida[e];
        f1[e] = sel ? 1.0f : 0.0f;
        f2[e] = sel ? -1.0f : -0.0f;
    }
    // Write-once streams: nt stores (native f32x4 vectors) skip L2 allocation.
    {
        f32x4 v0 = { f0[0], f0[1], f0[2], f0[3] };
        f32x4 v1 = { f1[0], f1[1], f1[2], f1[3] };
        f32x4 v2 = { f2[0], f2[1], f2[2], f2[3] };
        __builtin_nontemporal_store(v0, &reinterpret_cast<f32x4*>(o0)[tid]);
        __builtin_nontemporal_store(v1, &reinterpret_cast<f32x4*>(o1)[tid]);
        __builtin_nontemporal_store(v2, &reinterpret_cast<f32x4*>(o2)[tid]);
    }
}

extern "C" void kernel_launch(void* const* d_in, const int* in_sizes, int n_in,
                              void* d_out, int out_size, void* d_ws, size_t ws_size,
                              hipStream_t stream) {
    const int*   ids   = (const int*)d_in[0];     // (B,J,L) ids (int32/int64 auto-detect)
    const float* amask = (const float*)d_in[1];   // (B,J,2L) float32
    const float* uin   = (const float*)d_in[2];   // (B,J,L) float32
    float* out = (float*)d_out;                   // float32 x (3 * B*J*L)

    const int n_per = ROWS * L_LEN;               // 2,097,152 (hardcoded geometry)

    AttentionEssentialReinforce_51238959841470_kernel<<<dim3(ROWS), dim3(NT), 0, stream>>>(
        ids, amask, uin, out, n_per);
}

// Round 9
// 85.791 us; speedup vs baseline: 1.0147x; 1.0147x over previous
//
#include <hip/hip_runtime.h>

#define L_LEN 4096
#define NT 1024
#define ROWS 512               // B*J = 32*16 fixed by the reference
#define SLOP 96u               // f32-key error band (fast-log/div error <= ~8 ulps; 12x margin)
#define BCAP 256
#define NW (NT / 64)           // 16 waves

typedef float f32x4 __attribute__((ext_vector_type(4)));   // native vector for nt-store

// Round 19: re-land round 17 verbatim (best, 84.61 us). Round-18's nt LOADS
// regressed +2.4 us: load-side L2 bypass sits on the latency-critical path
// (loses L2 hits for the co-resident block + lengthens load-return latency
// the phase chain waits on). Store-side nt stays: nothing waits on stores.
// FINAL LEDGER: barrier-diet -1.1 | nt-stores -2.0 | fastmath -0.4(noise) |
// occupancy +0 | nt-loads +2.4 W | 2-row pipe +3.5 W | split +6.8 W.
// Dispatch tax ~5-7 us (r13). Kernel ~18 us vs ~11.5 us traffic+latency floor.
// NOT reapplied (round-9/10 cliff): hist+logf fusion, cnt-from-hist.
__global__ __launch_bounds__(NT, 8) void AttentionEssentialReinforce_51238959841470_kernel(
    const int* __restrict__ ids,       // int32 OR little-endian int64 (auto-detected)
    const float* __restrict__ amask,   // (ROWS, 2*L), only first half used
    const float* __restrict__ uin,     // (ROWS, L)
    float* __restrict__ out,           // float32: [ids | mask | -mask], n_per each
    int n_per)
{
    __shared__ unsigned int hist[4096];          // 16 KB (pass 0: 12-bit bins)
    __shared__ unsigned int h2[256];             // pass 1 bins (pre-zeroed early)
    __shared__ unsigned int s_cntw[NW], s_orw[NW], s_nhiw[NW], s_wtot[NW];
    __shared__ unsigned long long bkey[BCAP];    // band: exact f64 keys
    __shared__ int bidx[BCAP];                   // band: element indices
    __shared__ unsigned int s_remk, s_prefix, s_bn;

    const int row = blockIdx.x;
    const int tid = threadIdx.x;
    const int lane = tid & 63, wid = tid >> 6;
    const float* wrow = amask + (size_t)row * (2 * L_LEN);
    const float* urow = uin + (size_t)row * L_LEN;

    // ---- Issue the hot loads first; everything below overlaps their latency.
    float4 a0 = reinterpret_cast<const float4*>(wrow)[tid];
    float4 b0 = reinterpret_cast<const float4*>(urow)[tid];
    // int64-vs-int32 id detection: LE int64 ids (<2^31) have all-zero odd words.
    unsigned odd = ((const unsigned*)ids)[2 * tid + 1];

    // Zero histograms while the loads are in flight (off the critical path).
    #pragma unroll
    for (int b = 0; b < 4096 / NT; ++b) hist[tid + b * NT] = 0u;
    if (tid < 256) h2[tid] = 0u;
    if (tid == 0) s_bn = 0u;

    // ---- Phase 1: f32 keys in registers. r = max(w,1e-30)/(-ln u) is monotone-
    // equivalent to log(max(w,1e-30))+gumbel(u); positive-float IEEE bits are
    // order-isomorphic to value. Fast math here is safe: error <= ~8 ulps,
    // covered by the SLOP band; exactness restored in the f64 refine.
    float wv[4], uv[4];
    wv[0]=a0.x; wv[1]=a0.y; wv[2]=a0.z; wv[3]=a0.w;
    uv[0]=b0.x; uv[1]=b0.y; uv[2]=b0.z; uv[3]=b0.w;

    unsigned key[4];
    unsigned localnz = 0;
    #pragma unroll
    for (int e = 0; e < 4; ++e) {
        key[e] = 0u;                                  // w<=0 -> bottom, never selected
        if (wv[e] > 0.0f) {
            float t = -__logf(uv[e]);
            float r = __fdividef(fmaxf(wv[e], 1e-30f), t);
            key[e] = __float_as_uint(r);
            localnz++;
        }
    }
    {
        unsigned long long bal = __ballot(odd != 0u);
        unsigned v = localnz;
        #pragma unroll
        for (int off = 32; off > 0; off >>= 1) v += __shfl_down(v, off, 64);
        if (lane == 0) { s_cntw[wid] = v; s_orw[wid] = (bal != 0ull) ? 1u : 0u; }
    }
    __syncthreads();                                  // covers keys' wave sums + zeroing

    unsigned cnt = 0, orr = 0;
    #pragma unroll
    for (int w2 = 0; w2 < NW; ++w2) { cnt += s_cntw[w2]; orr |= s_orw[w2]; }
    const bool is64 = (orr == 0u);
    const int k = (int)floorf(0.15f * (float)cnt);    // f32(0.15)*f32(cnt), floored (as np)

    // Prefetch ids now: L2 latency overlaps the radix passes below.
    int ida[4];
    if (!is64) {
        int4 t0 = reinterpret_cast<const int4*>(ids + (size_t)row * L_LEN)[tid];
        ida[0]=t0.x; ida[1]=t0.y; ida[2]=t0.z; ida[3]=t0.w;
    } else {
        const longlong2* idr = reinterpret_cast<const longlong2*>(
            (const long long*)ids + (size_t)row * L_LEN);
        longlong2 a = idr[2 * tid], b = idr[2 * tid + 1];
        ida[0]=(int)a.x; ida[1]=(int)a.y; ida[2]=(int)b.x; ida[3]=(int)b.y;
    }

    unsigned lo_thr = 0xFFFFFFFFu, hi_thr = 0xFFFFFFFFu;   // k==0: select none
    int need = 0;
    unsigned bn = 0;

    if (k > 0) {
        // ---- Phase 2: localize the k-th largest f32 key to its 20-bit-prefix bin.
        // Pass 0: 12-bit field (bits 31:20), 4096 bins (pre-zeroed above).
        #pragma unroll
        for (int e = 0; e < 4; ++e) atomicAdd(&hist[key[e] >> 20], 1u);
        __syncthreads();
        {
            int b0i = 4095 - 4 * tid;                // 4 descending bins per thread
            unsigned c[4], lsum = 0;
            #pragma unroll
            for (int m = 0; m < 4; ++m) { c[m] = hist[b0i - m]; lsum += c[m]; }
            unsigned scan = lsum;
            #pragma unroll
            for (int off = 1; off < 64; off <<= 1) {
                unsigned o = __shfl_up(scan, (unsigned)off, 64);
                if (lane >= off) scan += o;
            }
            if (lane == 63) s_wtot[wid] = scan;
            __syncthreads();
            unsigned woff = 0;                       // inline cross-wave prefix (no barrier)
            #pragma unroll
            for (int w2 = 0; w2 < NW; ++w2) woff += (w2 < wid) ? s_wtot[w2] : 0u;
            unsigned run = woff + (scan - lsum);     // count in strictly-higher bins
            unsigned remk = (unsigned)k;
            #pragma unroll
            for (int m = 0; m < 4; ++m) {
                if (run < remk && run + c[m] >= remk) {   // exactly one (thread,m) hits
                    s_prefix = (unsigned)(b0i - m);
                    s_remk = remk - run;
                }
                run += c[m];
            }
        }
        __syncthreads();
        unsigned prefix12 = s_prefix;
        unsigned remk = s_remk;

        // Pass 1: 8-bit field (bits 19:12), 256 bins (h2, pre-zeroed), matching keys only.
        #pragma unroll
        for (int e = 0; e < 4; ++e)
            if ((key[e] >> 20) == prefix12)
                atomicAdd(&h2[(key[e] >> 12) & 0xFFu], 1u);
        __syncthreads();
        if (tid < 64) {                              // wave 0: descending-bin scan
            unsigned c[4], lsum = 0;
            #pragma unroll
            for (int m = 0; m < 4; ++m) { c[m] = h2[255 - 4 * tid - m]; lsum += c[m]; }
            unsigned scan = lsum;
            #pragma unroll
            for (int off = 1; off < 64; off <<= 1) {
                unsigned o = __shfl_up(scan, (unsigned)off, 64);
                if (tid >= off) scan += o;
            }
            unsigned run = scan - lsum;
            #pragma unroll
            for (int m = 0; m < 4; ++m) {
                if (run < remk && run + c[m] >= remk) {
                    s_prefix = (prefix12 << 8) | (unsigned)(255 - 4 * tid - m);
                }
                run += c[m];
            }
        }
        __syncthreads();
        const unsigned T20 = s_prefix;               // k-th key's 20-bit prefix
        const unsigned B_lo = T20 << 12, B_hi = (T20 << 12) | 0xFFFu;

        // ---- Error band: [B_lo - SLOP, B_hi + SLOP]. key > hi => certainly top-k;
        // key < lo => certainly not; band resolved exactly in f64 below.
        lo_thr = (B_lo > SLOP) ? B_lo - SLOP : 1u;   // >=1 excludes w<=0 sentinels
        hi_thr = B_hi + SLOP;                        // no overflow (keys <= 0x7F800000)
        unsigned nhi = 0;
        #pragma unroll
        for (int e = 0; e < 4; ++e) {
            if (key[e] > hi_thr) {
                nhi++;
            } else if (key[e] >= lo_thr) {
                unsigned pos = atomicAdd(&s_bn, 1u);
                if (pos < BCAP) {
                    double t = -log((double)uv[e]);
                    double r = (double)fmaxf(wv[e], 1e-30f) / t;   // exact-order key
                    bkey[pos] = (unsigned long long)__double_as_longlong(r);
                    bidx[pos] = 4 * tid + e;
                }
            }
        }
        {
            unsigned nv = nhi;
            #pragma unroll
            for (int off = 32; off > 0; off >>= 1) nv += __shfl_down(nv, off, 64);
            if (lane == 0) s_nhiw[wid] = nv;
        }
        __syncthreads();
        unsigned nhi_tot = 0;
        #pragma unroll
        for (int w2 = 0; w2 < NW; ++w2) nhi_tot += s_nhiw[w2];
        need = k - (int)nhi_tot;                     // >= 1; bn >= need by construction
        bn = s_bn; if (bn > BCAP) bn = BCAP;
    }

    // ---- Phase 3: selection + float32 outputs (non-temporal stores) ----
    const size_t obase = (size_t)row * L_LEN;
    float* o0 = out + obase;                      // masked ids
    float* o1 = out + (size_t)n_per + obase;      // mask
    float* o2 = out + 2 * (size_t)n_per + obase;  // -mask

    float f0[4], f1[4], f2[4];
    #pragma unroll
    for (int e = 0; e < 4; ++e) {
        bool sel;
        if (key[e] > hi_thr) {
            sel = true;
        } else if (key[e] < lo_thr) {
            sel = false;
        } else {
            // band member: rank by (f64 key desc, index asc) — stable, exact
            double t = -log((double)uv[e]);
            double r = (double)fmaxf(wv[e], 1e-30f) / t;
            unsigned long long myk = (unsigned long long)__double_as_longlong(r);
            int myi = 4 * tid + e;
            int rnk = 0;
            for (unsigned j = 0; j < bn; ++j)
                rnk += (bkey[j] > myk) || (bkey[j] == myk && bidx[j] < myi);
            sel = (rnk < need);
        }
        f0[e] = sel ? 103.0f : (float)ida[e];
        f1[e] = sel ? 1.0f : 0.0f;
        f2[e] = sel ? -1.0f : -0.0f;
    }
    // Write-once streams: nt stores (native f32x4 vectors) skip L2 allocation.
    {
        f32x4 v0 = { f0[0], f0[1], f0[2], f0[3] };
        f32x4 v1 = { f1[0], f1[1], f1[2], f1[3] };
        f32x4 v2 = { f2[0], f2[1], f2[2], f2[3] };
        __builtin_nontemporal_store(v0, &reinterpret_cast<f32x4*>(o0)[tid]);
        __builtin_nontemporal_store(v1, &reinterpret_cast<f32x4*>(o1)[tid]);
        __builtin_nontemporal_store(v2, &reinterpret_cast<f32x4*>(o2)[tid]);
    }
}

extern "C" void kernel_launch(void* const* d_in, const int* in_sizes, int n_in,
                              void* d_out, int out_size, void* d_ws, size_t ws_size,
                              hipStream_t stream) {
    const int*   ids   = (const int*)d_in[0];     // (B,J,L) ids (int32/int64 auto-detect)
    const float* amask = (const float*)d_in[1];   // (B,J,2L) float32
    const float* uin   = (const float*)d_in[2];   // (B,J,L) float32
    float* out = (float*)d_out;                   // float32 x (3 * B*J*L)

    const int n_per = ROWS * L_LEN;               // 2,097,152 (hardcoded geometry)

    AttentionEssentialReinforce_51238959841470_kernel<<<dim3(ROWS), dim3(NT), 0, stream>>>(
        ids, amask, uin, out, n_per);
}